// Round 1
// baseline (104.420 us; speedup 1.0000x reference)
//
#include <hip/hip_runtime.h>

typedef float2 cpx;

__device__ __forceinline__ cpx cmul(cpx a, cpx b){
  return make_float2(a.x*b.x - a.y*b.y, a.x*b.y + a.y*b.x);
}
__device__ __forceinline__ cpx cadd(cpx a, cpx b){ return make_float2(a.x+b.x, a.y+b.y); }

// M[4][4] (row-major, 16) = kron(A2x2, B2x2); index = (bitq<<1)|bitq1, A acts on bitq (top)
__device__ inline void kron2(const cpx* A, const cpx* B, cpx* M){
  for (int i2=0;i2<2;i2++) for (int k2=0;k2<2;k2++)
    for (int j2=0;j2<2;j2++) for (int l2=0;l2<2;l2++)
      M[(((i2<<1)|k2)<<2) + ((j2<<1)|l2)] = cmul(A[i2*2+j2], B[k2*2+l2]);
}

__device__ inline void mat4mul(const cpx* A, const cpx* B, cpx* C){
  for (int r=0;r<4;r++) for (int c=0;c<4;c++){
    cpx s = make_float2(0.f,0.f);
    for (int k=0;k<4;k++) s = cadd(s, cmul(A[r*4+k], B[k*4+c]));
    C[r*4+c]=s;
  }
}

// p: 1=X -> RY(-90) = [[c,c],[-c,c]], 2=Y -> RX(+90) = [[c,-ic],[-ic,c]], 3=Z -> I
__device__ inline void set_basis(int p, float C, cpx* B){
  if (p==1){ B[0]=make_float2(C,0.f); B[1]=make_float2(C,0.f); B[2]=make_float2(-C,0.f); B[3]=make_float2(C,0.f); }
  else if (p==2){ B[0]=make_float2(C,0.f); B[1]=make_float2(0.f,-C); B[2]=make_float2(0.f,-C); B[3]=make_float2(C,0.f); }
  else { B[0]=make_float2(1.f,0.f); B[1]=make_float2(0.f,0.f); B[2]=make_float2(0.f,0.f); B[3]=make_float2(1.f,0.f); }
}

// Build the 4x4 block unitary = product of the 15 two-local gates (thetas = params[0..14]).
// Pauli string for i in 1..15: pa = i>>2, pb = i&3 (0=I,1=X,2=Y,3=Z), matching
// ['IX','IY','IZ','XI','XX','XY','XZ','YI','YX','YY','YZ','ZI','ZX','ZY','ZZ'].
__global__ void build_u_kernel(const float* __restrict__ params, cpx* __restrict__ Uout){
  if (threadIdx.x != 0 || blockIdx.x != 0) return;
  cpx M[16], G[16], T[16];
  for (int k=0;k<16;k++) M[k] = make_float2((k%5==0)?1.f:0.f, 0.f);
  const float C = 0.70710678f;  // np.float32(cos(pi/4))
  for (int i=1;i<16;i++){
    float th = params[i-1];
    float h = 0.5f*th;
    float ch = cosf(h), sh = sinf(h);
    int pa = i>>2, pb = i&3;
    if (pa==0 || pb==0){
      // single-qubit rotation on wire q (pa) or q+1 (pb)
      int p = pa ? pa : pb;
      cpx R[4];
      if (p==1){ R[0]=make_float2(ch,0.f); R[1]=make_float2(0.f,-sh); R[2]=make_float2(0.f,-sh); R[3]=make_float2(ch,0.f); }       // RX
      else if (p==2){ R[0]=make_float2(ch,0.f); R[1]=make_float2(-sh,0.f); R[2]=make_float2(sh,0.f); R[3]=make_float2(ch,0.f); }  // RY
      else { R[0]=make_float2(ch,-sh); R[1]=make_float2(0.f,0.f); R[2]=make_float2(0.f,0.f); R[3]=make_float2(ch,sh); }           // RZ
      cpx I2[4] = {make_float2(1.f,0.f), make_float2(0.f,0.f), make_float2(0.f,0.f), make_float2(1.f,0.f)};
      if (pa) kron2(R, I2, G); else kron2(I2, R, G);
      mat4mul(G, M, T);
      for (int k=0;k<16;k++) M[k]=T[k];
    } else {
      // P (basis kron) ; CNOT ; RZ(theta) on q+1 ; CNOT ; P again (faithful: same P, not inverse)
      cpx BA[4], BB[4];
      set_basis(pa, C, BA); set_basis(pb, C, BB);
      kron2(BA, BB, G);
      mat4mul(G, M, T);
      for (int k=0;k<16;k++) M[k]=T[k];
      // CNOT * M  : swap rows 2,3
      for (int c2=0;c2<4;c2++){ cpx t=M[8+c2]; M[8+c2]=M[12+c2]; M[12+c2]=t; }
      // diag(e^-ih, e^ih, e^-ih, e^ih) * M  (RZ on wire q+1)
      {
        cpx em = make_float2(ch,-sh), ep = make_float2(ch,sh);
        for (int c2=0;c2<4;c2++){
          M[c2]   =cmul(em,M[c2]);    M[4+c2] =cmul(ep,M[4+c2]);
          M[8+c2] =cmul(em,M[8+c2]);  M[12+c2]=cmul(ep,M[12+c2]);
        }
      }
      // CNOT * M again
      for (int c2=0;c2<4;c2++){ cpx t=M[8+c2]; M[8+c2]=M[12+c2]; M[12+c2]=t; }
      mat4mul(G, M, T);
      for (int k=0;k<16;k++) M[k]=T[k];
    }
  }
  for (int k=0;k<16;k++) Uout[k]=M[k];
}

// psi after gate q=0 on |0...0>: column 0 of U at indices a*2^18, zero elsewhere.
__global__ __launch_bounds__(256) void init_gate0(cpx* __restrict__ psi, const cpx* __restrict__ Ug){
  unsigned i = blockIdx.x*256u + threadIdx.x;
  cpx v = make_float2(0.f,0.f);
  if ((i & 0x3FFFFu) == 0u) v = Ug[(i>>18)*4];  // U[r][0]
  psi[i] = v;
}

// Apply 4x4 U on bit pair (b0+1, b0). 2^18 threads, each owns one group of 4 amplitudes.
__global__ __launch_bounds__(256) void apply_gate(cpx* __restrict__ psi, const cpx* __restrict__ Ug, int b0){
  __shared__ cpx U[16];
  if (threadIdx.x < 16) U[threadIdx.x] = Ug[threadIdx.x];
  __syncthreads();
  unsigned t = blockIdx.x*256u + threadIdx.x;
  unsigned s0 = 1u << b0;
  unsigned low = t & (s0-1u);
  unsigned base = ((t >> b0) << (b0+2)) | low;
  cpx x0=psi[base], x1=psi[base+s0], x2=psi[base+2u*s0], x3=psi[base+3u*s0];
  cpx y0 = cadd(cadd(cmul(U[0],x0),cmul(U[1],x1)),cadd(cmul(U[2],x2),cmul(U[3],x3)));
  cpx y1 = cadd(cadd(cmul(U[4],x0),cmul(U[5],x1)),cadd(cmul(U[6],x2),cmul(U[7],x3)));
  cpx y2 = cadd(cadd(cmul(U[8],x0),cmul(U[9],x1)),cadd(cmul(U[10],x2),cmul(U[11],x3)));
  cpx y3 = cadd(cadd(cmul(U[12],x0),cmul(U[13],x1)),cadd(cmul(U[14],x2),cmul(U[15],x3)));
  psi[base]=y0; psi[base+s0]=y1; psi[base+2u*s0]=y2; psi[base+3u*s0]=y3;
}

// Gate q=18 (bits 1,0 -> 4 consecutive amplitudes) fused with |psi|^2 epilogue.
__global__ __launch_bounds__(256) void last_gate_probs(const cpx* __restrict__ psi, const cpx* __restrict__ Ug, float* __restrict__ out){
  __shared__ cpx U[16];
  if (threadIdx.x < 16) U[threadIdx.x] = Ug[threadIdx.x];
  __syncthreads();
  unsigned t = blockIdx.x*256u + threadIdx.x;
  const float4* pv = (const float4*)psi;
  float4 p01 = pv[t*2u], p23 = pv[t*2u+1u];
  cpx x0=make_float2(p01.x,p01.y), x1=make_float2(p01.z,p01.w);
  cpx x2=make_float2(p23.x,p23.y), x3=make_float2(p23.z,p23.w);
  cpx y0 = cadd(cadd(cmul(U[0],x0),cmul(U[1],x1)),cadd(cmul(U[2],x2),cmul(U[3],x3)));
  cpx y1 = cadd(cadd(cmul(U[4],x0),cmul(U[5],x1)),cadd(cmul(U[6],x2),cmul(U[7],x3)));
  cpx y2 = cadd(cadd(cmul(U[8],x0),cmul(U[9],x1)),cadd(cmul(U[10],x2),cmul(U[11],x3)));
  cpx y3 = cadd(cadd(cmul(U[12],x0),cmul(U[13],x1)),cadd(cmul(U[14],x2),cmul(U[15],x3)));
  ((float4*)out)[t] = make_float4(y0.x*y0.x+y0.y*y0.y, y1.x*y1.x+y1.y*y1.y,
                                  y2.x*y2.x+y2.y*y2.y, y3.x*y3.x+y3.y*y3.y);
}

extern "C" void kernel_launch(void* const* d_in, const int* in_sizes, int n_in,
                              void* d_out, int out_size, void* d_ws, size_t ws_size,
                              hipStream_t stream) {
  const float* params = (const float*)d_in[0];
  cpx* psi = (cpx*)d_ws;                                          // 2^20 cpx = 8 MB
  cpx* U   = (cpx*)((char*)d_ws + (size_t)(1u<<20)*sizeof(cpx));  // 16 cpx after psi

  build_u_kernel<<<1, 64, 0, stream>>>(params, U);
  init_gate0<<<(1u<<20)/256, 256, 0, stream>>>(psi, U);
  for (int q=1; q<=17; ++q){
    apply_gate<<<(1u<<18)/256, 256, 0, stream>>>(psi, U, 18-q);
  }
  last_gate_probs<<<(1u<<18)/256, 256, 0, stream>>>(psi, U, (float*)d_out);
}

// Round 2
// 54.170 us; speedup vs baseline: 1.9276x; 1.9276x over previous
//
#include <hip/hip_runtime.h>

typedef float2 cpx;

__device__ __forceinline__ cpx cmul(cpx a, cpx b){
  return make_float2(a.x*b.x - a.y*b.y, a.x*b.y + a.y*b.x);
}
__device__ __forceinline__ cpx cadd(cpx a, cpx b){ return make_float2(a.x+b.x, a.y+b.y); }
__device__ __forceinline__ cpx czero(){ return make_float2(0.f,0.f); }

// Basis-change matrix entry for composite two-local gates.
// p: 1=X -> RY(-90)=[[C,C],[-C,C]], 2=Y -> RX(+90)=[[C,-iC],[-iC,C]], 3=Z -> I
__device__ __forceinline__ cpx basis_e(int p, int i, int j){
  const float C = 0.70710678f;
  if (p==1){
    float v = (i==1 && j==0) ? -C : C;
    return make_float2(v, 0.f);
  } else if (p==2){
    if (i==j) return make_float2(C, 0.f);
    return make_float2(0.f, -C);
  } else {
    return make_float2(i==j ? 1.f : 0.f, 0.f);
  }
}

// Rotation entry: 1=RX, 2=RY, 3=RZ (half-angle ch, sh)
__device__ __forceinline__ cpx rot_e(int p, int i, int j, float ch, float sh){
  if (p==1){ // RX: [[ch, -i sh],[-i sh, ch]]
    if (i==j) return make_float2(ch, 0.f);
    return make_float2(0.f, -sh);
  } else if (p==2){ // RY: [[ch,-sh],[sh,ch]]
    if (i==j) return make_float2(ch, 0.f);
    return make_float2(i==1 ? sh : -sh, 0.f);
  } else { // RZ: diag(ch-ish, ch+ish)
    if (i!=j) return czero();
    return make_float2(ch, i==0 ? -sh : sh);
  }
}

// One-block setup kernel:
//  1. Build 4x4 block unitary U (16 threads in parallel, composite gates as P*diag*P).
//  2. Build col0/col1 (256 each): gates b=6..0 applied to e_0 / e_128.
//  3. Build w (8192): gates b'=11..0 applied to e_0 (sparsity-pruned).
// Outputs: w_out[8192], cols_out[512] (col0 then col1).
__global__ __launch_bounds__(256) void setup_kernel(const float* __restrict__ params,
                                                    cpx* __restrict__ w_out,
                                                    cpx* __restrict__ cols_out){
  __shared__ cpx Ma[16], Mb[16], U[16];
  __shared__ cpx cols[512];
  __shared__ cpx w[8192];
  const int t = threadIdx.x;

  // ---- init ----
  if (t < 16) Ma[t] = make_float2((t%5==0)?1.f:0.f, 0.f);
  for (int k=t; k<8192; k+=256) w[k] = czero();
  for (int k=t; k<512; k+=256) cols[k] = czero();
  if (t == 0){ w[0] = make_float2(1.f,0.f); cols[0] = make_float2(1.f,0.f); cols[256+128] = make_float2(1.f,0.f); }
  __syncthreads();

  // ---- build U: M <- G_i * M for i=1..15 ----
  cpx* src = Ma; cpx* dst = Mb;
  for (int i=1; i<16; ++i){
    float th = params[i-1];
    float h = 0.5f*th;
    float ch = cosf(h), sh = sinf(h);
    int pa = i>>2, pb = i&3;
    if (t < 16){
      int r = t>>2, c = t&3;
      cpx Grow[4];
      if (pa==0 || pb==0){
        int p = pa ? pa : pb;
        for (int k=0;k<4;k++){
          if (pa) Grow[k] = ((r&1)==(k&1)) ? rot_e(p, r>>1, k>>1, ch, sh) : czero();
          else    Grow[k] = ((r>>1)==(k>>1)) ? rot_e(p, r&1, k&1, ch, sh) : czero();
        }
      } else {
        // G = P * diag(em,ep,ep,em) * P, P = kron(BA,BB)
        cpx em = make_float2(ch,-sh), ep = make_float2(ch, sh);
        for (int k=0;k<4;k++){
          cpx s = czero();
          for (int m=0;m<4;m++){
            cpx Prm = cmul(basis_e(pa, r>>1, m>>1), basis_e(pb, r&1, m&1));
            cpx Pmk = cmul(basis_e(pa, m>>1, k>>1), basis_e(pb, m&1, k&1));
            cpx d = (m==0 || m==3) ? em : ep;
            s = cadd(s, cmul(cmul(Prm, d), Pmk));
          }
          Grow[k] = s;
        }
      }
      cpx s = czero();
      for (int k=0;k<4;k++) s = cadd(s, cmul(Grow[k], src[k*4 + c]));
      dst[t] = s;
    }
    __syncthreads();
    cpx* tmp = src; src = dst; dst = tmp;
  }
  if (t < 16) U[t] = src[t];
  __syncthreads();

  // ---- cols cascade: gates b=6..0 on 256-dim, both columns (dense, 128 threads) ----
  for (int b=6; b>=0; --b){
    if (t < 128){
      int which = t>>6, g = t&63;
      cpx* v = cols + which*256;
      unsigned s0 = 1u<<b;
      unsigned base = (((unsigned)g >> b) << (b+2)) | ((unsigned)g & (s0-1u));
      cpx x0=v[base], x1=v[base+s0], x2=v[base+2u*s0], x3=v[base+3u*s0];
      cpx y0 = cadd(cadd(cmul(U[0],x0),cmul(U[1],x1)),cadd(cmul(U[2],x2),cmul(U[3],x3)));
      cpx y1 = cadd(cadd(cmul(U[4],x0),cmul(U[5],x1)),cadd(cmul(U[6],x2),cmul(U[7],x3)));
      cpx y2 = cadd(cadd(cmul(U[8],x0),cmul(U[9],x1)),cadd(cmul(U[10],x2),cmul(U[11],x3)));
      cpx y3 = cadd(cadd(cmul(U[12],x0),cmul(U[13],x1)),cadd(cmul(U[14],x2),cmul(U[15],x3)));
      v[base]=y0; v[base+s0]=y1; v[base+2u*s0]=y2; v[base+3u*s0]=y3;
    }
    __syncthreads();
  }

  // ---- w cascade: gates b'=11..0 on 8192-dim, sparsity-pruned ----
  // Before gate b', support = {h : bits b'..0 == 0}; active groups have low b' bits == 0.
  for (int b=11; b>=0; --b){
    unsigned s0 = 1u<<b;
    int ng = 2048 >> b;           // number of active groups
    for (int k=t; k<ng; k+=256){
      unsigned base = ((unsigned)k) << (b+2);   // g = k<<b, low bits zero
      cpx x0=w[base], x1=w[base+s0], x2=w[base+2u*s0], x3=w[base+3u*s0];
      cpx y0 = cadd(cadd(cmul(U[0],x0),cmul(U[1],x1)),cadd(cmul(U[2],x2),cmul(U[3],x3)));
      cpx y1 = cadd(cadd(cmul(U[4],x0),cmul(U[5],x1)),cadd(cmul(U[6],x2),cmul(U[7],x3)));
      cpx y2 = cadd(cadd(cmul(U[8],x0),cmul(U[9],x1)),cadd(cmul(U[10],x2),cmul(U[11],x3)));
      cpx y3 = cadd(cadd(cmul(U[12],x0),cmul(U[13],x1)),cadd(cmul(U[14],x2),cmul(U[15],x3)));
      w[base]=y0; w[base+s0]=y1; w[base+2u*s0]=y2; w[base+3u*s0]=y3;
    }
    __syncthreads();
  }

  // ---- write out ----
  for (int k=t; k<8192; k+=256) w_out[k] = w[k];
  for (int k=t; k<512;  k+=256) cols_out[k] = cols[k];
}

// Final streaming kernel: out[c*256+j] = |w[2c]*col0[j] + w[2c+1]*col1[j]|^2
// 2^18 threads, 4 outputs each (one float4 store). Each wave covers exactly one chunk.
__global__ __launch_bounds__(256) void probs_kernel(const cpx* __restrict__ w,
                                                    const cpx* __restrict__ cols,
                                                    float* __restrict__ out){
  unsigned tid = blockIdx.x*256u + threadIdx.x;
  unsigned o = tid * 4u;          // output base index
  unsigned c = o >> 8;            // chunk = bits 19..8
  unsigned j = o & 255u;          // within-chunk index, multiple of 4
  cpx w0 = w[2u*c], w1 = w[2u*c + 1u];
  const float4* c0 = (const float4*)(cols + j);         // col0[j..j+3] = 2 float4
  const float4* c1 = (const float4*)(cols + 256 + j);   // col1[j..j+3]
  float4 a0 = c0[0], a1 = c0[1];
  float4 b0 = c1[0], b1 = c1[1];
  float4 r;
  {
    cpx y = cadd(cmul(w0, make_float2(a0.x,a0.y)), cmul(w1, make_float2(b0.x,b0.y)));
    r.x = y.x*y.x + y.y*y.y;
    y = cadd(cmul(w0, make_float2(a0.z,a0.w)), cmul(w1, make_float2(b0.z,b0.w)));
    r.y = y.x*y.x + y.y*y.y;
    y = cadd(cmul(w0, make_float2(a1.x,a1.y)), cmul(w1, make_float2(b1.x,b1.y)));
    r.z = y.x*y.x + y.y*y.y;
    y = cadd(cmul(w0, make_float2(a1.z,a1.w)), cmul(w1, make_float2(b1.z,b1.w)));
    r.w = y.x*y.x + y.y*y.y;
  }
  ((float4*)out)[tid] = r;
}

extern "C" void kernel_launch(void* const* d_in, const int* in_sizes, int n_in,
                              void* d_out, int out_size, void* d_ws, size_t ws_size,
                              hipStream_t stream) {
  const float* params = (const float*)d_in[0];
  cpx* w    = (cpx*)d_ws;                                   // 8192 cpx = 64 KB
  cpx* cols = (cpx*)((char*)d_ws + 8192*sizeof(cpx));       // 512 cpx = 4 KB

  setup_kernel<<<1, 256, 0, stream>>>(params, w, cols);
  probs_kernel<<<(1u<<18)/256, 256, 0, stream>>>(w, cols, (float*)d_out);
}

// Round 4
// 16.419 us; speedup vs baseline: 6.3596x; 3.2991x over previous
//
#include <hip/hip_runtime.h>

typedef float2 cpx;

__device__ __forceinline__ cpx cmul(cpx a, cpx b){
  return make_float2(a.x*b.x - a.y*b.y, a.x*b.y + a.y*b.x);
}
__device__ __forceinline__ cpx cadd(cpx a, cpx b){ return make_float2(a.x+b.x, a.y+b.y); }
__device__ __forceinline__ cpx czero(){ return make_float2(0.f,0.f); }

// p: 1=X -> RY(-90)=[[C,C],[-C,C]], 2=Y -> RX(+90)=[[C,-iC],[-iC,C]], 3=Z -> I
__device__ __forceinline__ cpx basis_e(int p, int i, int j){
  const float C = 0.70710678f;
  if (p==1){ float s = (i==1 && j==0) ? -C : C; return make_float2(s, 0.f); }
  else if (p==2){ if (i==j) return make_float2(C,0.f); return make_float2(0.f,-C); }
  else { return make_float2(i==j ? 1.f : 0.f, 0.f); }
}

// 1=RX, 2=RY, 3=RZ (half-angle ch, sh)
__device__ __forceinline__ cpx rot_e(int p, int i, int j, float ch, float sh){
  if (p==1){ if (i==j) return make_float2(ch,0.f); return make_float2(0.f,-sh); }
  else if (p==2){ if (i==j) return make_float2(ch,0.f); return make_float2(i==1?sh:-sh, 0.f); }
  else { if (i!=j) return czero(); return make_float2(ch, i==0?-sh:sh); }
}

// Fully fused: every block redundantly builds U + the three small cascade vectors
// in its own LDS (~11 KB), then writes its 1024-float slice of |psi|^2.
// Factorization: out[c*256+j] = | sum_z w_z * col_z[j] |^2,
//   w_z = sum_y v[2*(c>>6)+y] * col2_y[ ((c&63)<<1) | z ],
//   v    = gates b'=11..6 of the 13-bit space (128-dim, from e0)
//   col2 = gates b'=5..0  (128-dim, from e0 and e64)
//   col  = gates b =6..0  of the 20-bit space (256-dim, from e0 and e128)
__global__ __launch_bounds__(256) void mps_fused(const float* __restrict__ params,
                                                 float* __restrict__ out){
  __shared__ __align__(16) cpx Gm[16][16];   // gate matrices, slots 1..15
  __shared__ __align__(16) cpx W1[8][16];
  __shared__ __align__(16) cpx W2[4][16];
  __shared__ __align__(16) cpx W3[2][16];
  __shared__ __align__(16) cpx Us[16];
  __shared__ __align__(16) cpx col[512];     // col0 @0, col1 @256 (seed e128 -> slot 384)
  __shared__ __align__(16) cpx col2[256];    // col2_0 @0, col2_1 @128 (seed e64 -> slot 192)
  __shared__ __align__(16) cpx v[128];
  const int t = threadIdx.x;
  const cpx one = make_float2(1.f,0.f);

  // ---- init cascade vectors; seeds written by the OWNING thread (race-free) ----
  for (int k=t; k<512; k+=256) col[k] = (k==0 || k==384) ? one : czero();
  if (t < 256) col2[t] = (t==0 || t==192) ? one : czero();
  if (t < 128) v[t] = (t==0) ? one : czero();

  // ---- build all 15 gate matrices in parallel (threads 0..239) ----
  if (t < 240){
    int i = (t>>4) + 1;          // gate index 1..15
    int e = t & 15;
    int r = e>>2, c = e&3;
    float th = params[i-1];
    float h = 0.5f*th;
    float ch = cosf(h), sh = sinf(h);
    int pa = i>>2, pb = i&3;     // 0=I,1=X,2=Y,3=Z
    cpx g;
    if (pa==0 || pb==0){
      int p = pa ? pa : pb;
      if (pa) g = ((r&1)==(c&1))   ? rot_e(p, r>>1, c>>1, ch, sh) : czero();
      else    g = ((r>>1)==(c>>1)) ? rot_e(p, r&1,  c&1,  ch, sh) : czero();
    } else {
      // G = P * diag(em,ep,ep,em) * P,  P = kron(BA,BB) (faithful: same P both sides)
      cpx em = make_float2(ch,-sh), ep = make_float2(ch,sh);
      cpx s = czero();
      for (int m=0;m<4;m++){
        cpx Prm = cmul(basis_e(pa, r>>1, m>>1), basis_e(pb, r&1, m&1));
        cpx Pmc = cmul(basis_e(pa, m>>1, c>>1), basis_e(pb, m&1, c&1));
        cpx d = (m==0 || m==3) ? em : ep;
        s = cadd(s, cmul(cmul(Prm, d), Pmc));
      }
      g = s;
    }
    Gm[i][e] = g;
  }
  __syncthreads();

  // ---- order-preserving tree product: U = G15*G14*...*G1 ----
  // L1: P_p = G_{2p+2}*G_{2p+1} (p=0..6), P_7 = G15
  if (t < 128){
    int p = t>>4, e = t&15, r = e>>2, c = e&3;
    if (p < 7){
      cpx s = czero();
      for (int k=0;k<4;k++) s = cadd(s, cmul(Gm[2*p+2][r*4+k], Gm[2*p+1][k*4+c]));
      W1[p][e] = s;
    } else {
      W1[7][e] = Gm[15][e];
    }
  }
  __syncthreads();
  if (t < 64){
    int p = t>>4, e = t&15, r = e>>2, c = e&3;
    cpx s = czero();
    for (int k=0;k<4;k++) s = cadd(s, cmul(W1[2*p+1][r*4+k], W1[2*p][k*4+c]));
    W2[p][e] = s;
  }
  __syncthreads();
  if (t < 32){
    int p = t>>4, e = t&15, r = e>>2, c = e&3;
    cpx s = czero();
    for (int k=0;k<4;k++) s = cadd(s, cmul(W2[2*p+1][r*4+k], W2[2*p][k*4+c]));
    W3[p][e] = s;
  }
  __syncthreads();
  if (t < 16){
    int r = t>>2, c = t&3;
    cpx s = czero();
    for (int k=0;k<4;k++) s = cadd(s, cmul(W3[1][r*4+k], W3[0][k*4+c]));
    Us[t] = s;
  }

  // ---- three cascades, concurrent across waves, 7 barrier steps ----
  const int wv = t>>6, l = t&63;
  for (int s=0; s<7; ++s){
    __syncthreads();
    cpx *vv = nullptr; unsigned base=0, s0=0;
    if (wv==0 || wv==1){                 // col0 / col1: b = 6..0, 64 groups
      int b = 6-s;
      s0 = 1u<<b;
      unsigned g = (unsigned)l;
      base = ((g>>b)<<(b+2)) | (g & (s0-1u));
      vv = col + (wv<<8);
    } else if (wv==2 && s<6){            // col2 both columns: b = 5..0, 2x32 groups
      int b = 5-s;
      s0 = 1u<<b;
      unsigned g = (unsigned)(l & 31);
      base = ((g>>b)<<(b+2)) | (g & (s0-1u));
      vv = col2 + ((l>>5)<<7);
    } else if (wv==3 && s<6 && l<32){    // v: b = 5..0, 32 groups
      int b = 5-s;
      s0 = 1u<<b;
      unsigned g = (unsigned)l;
      base = ((g>>b)<<(b+2)) | (g & (s0-1u));
      vv = v;
    }
    if (vv){
      cpx x0=vv[base], x1=vv[base+s0], x2=vv[base+2u*s0], x3=vv[base+3u*s0];
      cpx y0 = cadd(cadd(cmul(Us[0],x0),cmul(Us[1],x1)),cadd(cmul(Us[2],x2),cmul(Us[3],x3)));
      cpx y1 = cadd(cadd(cmul(Us[4],x0),cmul(Us[5],x1)),cadd(cmul(Us[6],x2),cmul(Us[7],x3)));
      cpx y2 = cadd(cadd(cmul(Us[8],x0),cmul(Us[9],x1)),cadd(cmul(Us[10],x2),cmul(Us[11],x3)));
      cpx y3 = cadd(cadd(cmul(Us[12],x0),cmul(Us[13],x1)),cadd(cmul(Us[14],x2),cmul(Us[15],x3)));
      vv[base]=y0; vv[base+s0]=y1; vv[base+2u*s0]=y2; vv[base+3u*s0]=y3;
    }
  }
  __syncthreads();

  // ---- combine + write slice: block bid covers c = 4*bid .. 4*bid+3, all j ----
  unsigned ci = (unsigned)(t>>6);
  unsigned c  = (blockIdx.x<<2) | ci;       // 12-bit chunk index
  unsigned jp = ((unsigned)(t&63))<<2;      // j base (multiple of 4)
  unsigned c3 = c>>6;
  unsigned m0 = (c&63u)<<1;
  cpx v0 = v[2u*c3], v1 = v[2u*c3+1u];
  cpx w0 = cadd(cmul(v0, col2[m0]),     cmul(v1, col2[128u+m0]));
  cpx w1 = cadd(cmul(v0, col2[m0+1u]),  cmul(v1, col2[128u+m0+1u]));
  float4 a0 = *(const float4*)(col + jp);
  float4 a1 = *(const float4*)(col + jp + 2);
  float4 b0 = *(const float4*)(col + 256 + jp);
  float4 b1 = *(const float4*)(col + 256 + jp + 2);
  float4 r;
  cpx y;
  y = cadd(cmul(w0, make_float2(a0.x,a0.y)), cmul(w1, make_float2(b0.x,b0.y)));
  r.x = y.x*y.x + y.y*y.y;
  y = cadd(cmul(w0, make_float2(a0.z,a0.w)), cmul(w1, make_float2(b0.z,b0.w)));
  r.y = y.x*y.x + y.y*y.y;
  y = cadd(cmul(w0, make_float2(a1.x,a1.y)), cmul(w1, make_float2(b1.x,b1.y)));
  r.z = y.x*y.x + y.y*y.y;
  y = cadd(cmul(w0, make_float2(a1.z,a1.w)), cmul(w1, make_float2(b1.z,b1.w)));
  r.w = y.x*y.x + y.y*y.y;
  ((float4*)out)[(blockIdx.x<<8) | (unsigned)t] = r;
}

extern "C" void kernel_launch(void* const* d_in, const int* in_sizes, int n_in,
                              void* d_out, int out_size, void* d_ws, size_t ws_size,
                              hipStream_t stream) {
  const float* params = (const float*)d_in[0];
  mps_fused<<<1024, 256, 0, stream>>>(params, (float*)d_out);
}